// Round 1
// baseline (246.812 us; speedup 1.0000x reference)
//
#include <hip/hip_runtime.h>
#include <hip/hip_bf16.h>

#define B_   4
#define S_   1024
#define HID_ 1024
#define H_   16
#define D_   64

typedef __attribute__((ext_vector_type(4))) float f32x4;
typedef __attribute__((ext_vector_type(8))) __bf16 bf16v8;
typedef __attribute__((ext_vector_type(8))) unsigned short u16x8;

#define MFMA16(a, b, c) __builtin_amdgcn_mfma_f32_16x16x32_bf16((a), (b), (c), 0, 0, 0)

__device__ __forceinline__ unsigned short f2bs(float f) {
    union { float f; unsigned u; } v; v.f = f;
    unsigned r = v.u + 0x7fffu + ((v.u >> 16) & 1u);   // RNE
    return (unsigned short)(r >> 16);
}
__device__ __forceinline__ float bs2f(unsigned short s) {
    union { unsigned u; float f; } v; v.u = ((unsigned)s) << 16;
    return v.f;
}

// ---------------------------------------------------------------------------
// Kernel 1: dist_emb f32 -> bf16 (done once per launch; tiny)
// ---------------------------------------------------------------------------
__global__ void conv_e_kernel(const float* __restrict__ E, unsigned short* __restrict__ Eb) {
    int i = (blockIdx.x * 256 + threadIdx.x) * 4;
    const int n = 2047 * 64;
    if (i + 3 < n) {
        float4 x = *(const float4*)(E + i);
        Eb[i + 0] = f2bs(x.x); Eb[i + 1] = f2bs(x.y);
        Eb[i + 2] = f2bs(x.z); Eb[i + 3] = f2bs(x.w);
    } else {
        for (int k = i; k < n; ++k) Eb[k] = f2bs(E[k]);
    }
}

// ---------------------------------------------------------------------------
// Kernel 2: fused QKV projection GEMM.
// C[4096,3072] = X[4096,1024] @ [Wq;Wk;Wv]^T, written as bf16 [B,H,S,D].
// 128x128 tiles, BK=32, 4 waves (2x2), 16x16x32 bf16 MFMA.
// ---------------------------------------------------------------------------
__global__ __launch_bounds__(256)
void proj_kernel(const float* __restrict__ X,
                 const float* __restrict__ Wq, const float* __restrict__ bq,
                 const float* __restrict__ Wk, const float* __restrict__ bk,
                 const float* __restrict__ Wv, const float* __restrict__ bv,
                 unsigned short* __restrict__ Qo, unsigned short* __restrict__ Ko,
                 unsigned short* __restrict__ Vo)
{
    __shared__ unsigned short Al[128][40];   // 32 k + 8 pad (80B rows, 16B-aligned)
    __shared__ unsigned short Bl[128][40];

    const int tile = blockIdx.x;
    const int rt = tile / 24, ct = tile % 24;
    const int row0 = rt * 128, col0 = ct * 128;
    const int which = col0 >> 10;                 // 0:q 1:k 2:v
    const float* Wm   = (which == 0) ? Wq : (which == 1) ? Wk : Wv;
    const float* bias = (which == 0) ? bq : (which == 1) ? bk : bv;
    unsigned short* Out = (which == 0) ? Qo : (which == 1) ? Ko : Vo;
    const int oc0 = col0 & 1023;

    const int t = threadIdx.x;
    const int lane = t & 63, wv = t >> 6;
    const int wr = wv >> 1, wc = wv & 1;
    const int lg = lane >> 4, lc = lane & 15;

    f32x4 acc[4][4] = {};

    for (int k0 = 0; k0 < 1024; k0 += 32) {
        __syncthreads();
#pragma unroll
        for (int l = 0; l < 4; ++l) {
            int idx = l * 256 + t;                 // [0,1024) float4s
            int r = idx >> 3, kq = (idx & 7) * 4;
            float4 a = *(const float4*)(X  + (size_t)(row0 + r) * 1024 + k0 + kq);
            float4 b = *(const float4*)(Wm + (size_t)(oc0  + r) * 1024 + k0 + kq);
            short4 as, bs;
            as.x = (short)f2bs(a.x); as.y = (short)f2bs(a.y);
            as.z = (short)f2bs(a.z); as.w = (short)f2bs(a.w);
            bs.x = (short)f2bs(b.x); bs.y = (short)f2bs(b.y);
            bs.z = (short)f2bs(b.z); bs.w = (short)f2bs(b.w);
            *(short4*)&Al[r][kq] = as;
            *(short4*)&Bl[r][kq] = bs;
        }
        __syncthreads();
        bf16v8 af[4], bfg[4];
#pragma unroll
        for (int m = 0; m < 4; ++m) af[m]  = *(const bf16v8*)&Al[wr * 64 + m * 16 + lc][lg * 8];
#pragma unroll
        for (int n = 0; n < 4; ++n) bfg[n] = *(const bf16v8*)&Bl[wc * 64 + n * 16 + lc][lg * 8];
#pragma unroll
        for (int m = 0; m < 4; ++m)
#pragma unroll
            for (int n = 0; n < 4; ++n)
                acc[m][n] = MFMA16(af[m], bfg[n], acc[m][n]);
    }

    // epilogue: bias + scatter into [B,H,S,D] bf16
#pragma unroll
    for (int m = 0; m < 4; ++m)
#pragma unroll
        for (int n = 0; n < 4; ++n) {
            int j = oc0 + wc * 64 + n * 16 + lc;   // within-matrix col [0,1024)
            int hh = j >> 6, dd = j & 63;
            float bv_ = bias[j];
#pragma unroll
            for (int r = 0; r < 4; ++r) {
                int i = row0 + wr * 64 + m * 16 + lg * 4 + r;
                int bb = i >> 10, ss = i & 1023;
                float v = acc[m][n][r] + bv_;
                Out[((size_t)(bb * 16 + hh) * 1024 + ss) * 64 + dd] = f2bs(v);
            }
        }
}

// ---------------------------------------------------------------------------
// Kernel 3: fused attention with relative_key_query bias.
// Block = one (b,h) x 64 q-rows; 4 waves, each owns 16 q-rows.
// Iterate 64-col K/V tiles; QD/KD rel GEMMs into LDS; skew-gather; online
// softmax; PV via LDS-transposed P.
// ---------------------------------------------------------------------------
__global__ __launch_bounds__(256)
void attn_kernel(const unsigned short* __restrict__ Q,
                 const unsigned short* __restrict__ K,
                 const unsigned short* __restrict__ V,
                 const float* __restrict__ mask,
                 const unsigned short* __restrict__ Eb,
                 float* __restrict__ Out)
{
    __shared__ unsigned short Kl[64][72];     // K tile  [j][dim]
    __shared__ unsigned short VTl[64][72];    // V^T tile [dim][j]
    __shared__ unsigned short El[128][72];    // E window [dcol][dim]
    __shared__ unsigned short QDl[64][132];   // QD [i][dcol]
    __shared__ unsigned short KDl[64][132];   // KD [j][dcol]
    __shared__ float maskl[64];
    __shared__ unsigned short Pl[4][16][72];  // per-wave P [i][j]

    const int t = threadIdx.x;
    const int lane = t & 63;
    const int w = t >> 6;
    const int lg = lane >> 4, lc = lane & 15;

    const int qt = blockIdx.x;       // 0..15
    const int bh = blockIdx.y;       // 0..63
    const int b = bh >> 4, h = bh & 15;
    const int i0 = qt * 64;

    const unsigned short* Qh = Q + (size_t)bh * S_ * D_;
    const unsigned short* Kh = K + (size_t)bh * S_ * D_;
    const unsigned short* Vh = V + (size_t)bh * S_ * D_;

    // this wave's Q fragments (A-operand), rows i0 + w*16 + [0,16)
    bf16v8 qf[2];
#pragma unroll
    for (int ks = 0; ks < 2; ++ks)
        qf[ks] = *(const bf16v8*)(Qh + (size_t)(i0 + w * 16 + lc) * D_ + ks * 32 + lg * 8);

    float m_r[4], l_r[4];
    f32x4 ctx[4];
#pragma unroll
    for (int r = 0; r < 4; ++r) { m_r[r] = -1e30f; l_r[r] = 0.f; }
#pragma unroll
    for (int nd = 0; nd < 4; ++nd) ctx[nd] = (f32x4){0.f, 0.f, 0.f, 0.f};

    for (int jt = 0; jt < 16; ++jt) {
        const int j0 = jt * 64;
        const int dbase = i0 - j0 + 960;   // window start in dist index space
        __syncthreads();                    // protect LDS vs previous iter readers

        // ---- stage K tile and V^T tile ----
#pragma unroll
        for (int l = 0; l < 2; ++l) {
            int idx = l * 256 + t;          // [0,512)
            int r = idx >> 3, cq = (idx & 7) * 8;
            u16x8 kv = *(const u16x8*)(Kh + (size_t)(j0 + r) * D_ + cq);
            *(u16x8*)&Kl[r][cq] = kv;
            u16x8 vv = *(const u16x8*)(Vh + (size_t)(j0 + r) * D_ + cq);
#pragma unroll
            for (int e = 0; e < 8; ++e) VTl[cq + e][r] = vv[e];
        }
        // ---- stage E window (already bf16) ----
        {
            int er = t >> 1, co = (t & 1) * 32;
            int gr = dbase + er; if (gr > 2046) gr = 2046;   // pad row, never gathered
            const unsigned short* src = Eb + (size_t)gr * 64 + co;
#pragma unroll
            for (int qq = 0; qq < 4; ++qq)
                *(u16x8*)&El[er][co + qq * 8] = *(const u16x8*)(src + qq * 8);
        }
        if (t < 64) maskl[t] = mask[(size_t)b * S_ + j0 + t];
        __syncthreads();

        // ---- QD = Q_tile @ E_win^T, KD = K_tile @ E_win^T ----
        bf16v8 kfa[2];
#pragma unroll
        for (int ks = 0; ks < 2; ++ks)
            kfa[ks] = *(const bf16v8*)&Kl[w * 16 + lc][ks * 32 + lg * 8];
        f32x4 qd[8], kd[8];
#pragma unroll
        for (int nd = 0; nd < 8; ++nd) {
            qd[nd] = (f32x4){0.f, 0.f, 0.f, 0.f};
            kd[nd] = (f32x4){0.f, 0.f, 0.f, 0.f};
#pragma unroll
            for (int ks = 0; ks < 2; ++ks) {
                bf16v8 ef = *(const bf16v8*)&El[nd * 16 + lc][ks * 32 + lg * 8];
                qd[nd] = MFMA16(qf[ks],  ef, qd[nd]);
                kd[nd] = MFMA16(kfa[ks], ef, kd[nd]);
            }
        }
#pragma unroll
        for (int nd = 0; nd < 8; ++nd)
#pragma unroll
            for (int r = 0; r < 4; ++r) {
                int row = w * 16 + lg * 4 + r;
                QDl[row][nd * 16 + lc] = f2bs(qd[nd][r]);
                KDl[row][nd * 16 + lc] = f2bs(kd[nd][r]);
            }
        __syncthreads();

        // ---- S = Q K^T ----
        f32x4 s[4];
#pragma unroll
        for (int n = 0; n < 4; ++n) {
            s[n] = (f32x4){0.f, 0.f, 0.f, 0.f};
#pragma unroll
            for (int ks = 0; ks < 2; ++ks) {
                bf16v8 kb = *(const bf16v8*)&Kl[n * 16 + lc][ks * 32 + lg * 8];
                s[n] = MFMA16(qf[ks], kb, s[n]);
            }
        }

        // ---- rel bias + mask + online softmax ----
        float mnew[4], alpha[4], rs[4];
#pragma unroll
        for (int r = 0; r < 4; ++r) {
            const int gi = w * 16 + lg * 4 + r;    // row within 64-tile
            float mx = m_r[r];
#pragma unroll
            for (int n = 0; n < 4; ++n) {
                int j = n * 16 + lc;
                int widx = gi - j + 63;            // in [0,126]
                float val = (s[n][r] + bs2f(QDl[gi][widx]) + bs2f(KDl[j][widx])) * 0.125f
                            + maskl[j];
                s[n][r] = val;
                mx = fmaxf(mx, val);
            }
#pragma unroll
            for (int off = 1; off < 16; off <<= 1)
                mx = fmaxf(mx, __shfl_xor(mx, off));
            mnew[r] = mx;
            alpha[r] = __expf(m_r[r] - mx);
            m_r[r] = mx;
            rs[r] = 0.f;
        }
#pragma unroll
        for (int n = 0; n < 4; ++n)
#pragma unroll
            for (int r = 0; r < 4; ++r) {
                float p = __expf(s[n][r] - mnew[r]);
                s[n][r] = p;
                rs[r] += p;
            }
#pragma unroll
        for (int r = 0; r < 4; ++r) {
#pragma unroll
            for (int off = 1; off < 16; off <<= 1)
                rs[r] += __shfl_xor(rs[r], off);
            l_r[r] = l_r[r] * alpha[r] + rs[r];
        }
#pragma unroll
        for (int nd = 0; nd < 4; ++nd)
#pragma unroll
            for (int r = 0; r < 4; ++r)
                ctx[nd][r] *= alpha[r];

        // ---- P -> LDS (bf16), PV ----
#pragma unroll
        for (int n = 0; n < 4; ++n)
#pragma unroll
            for (int r = 0; r < 4; ++r)
                Pl[w][lg * 4 + r][n * 16 + lc] = f2bs(s[n][r]);
        bf16v8 pf[2];
#pragma unroll
        for (int ks = 0; ks < 2; ++ks)
            pf[ks] = *(const bf16v8*)&Pl[w][lc][ks * 32 + lg * 8];
#pragma unroll
        for (int nd = 0; nd < 4; ++nd)
#pragma unroll
            for (int ks = 0; ks < 2; ++ks) {
                bf16v8 vf = *(const bf16v8*)&VTl[nd * 16 + lc][ks * 32 + lg * 8];
                ctx[nd] = MFMA16(pf[ks], vf, ctx[nd]);
            }
    }

    // ---- epilogue: normalize, write [B,S,H*D] f32 ----
#pragma unroll
    for (int r = 0; r < 4; ++r) l_r[r] = 1.0f / l_r[r];
#pragma unroll
    for (int nd = 0; nd < 4; ++nd)
#pragma unroll
        for (int r = 0; r < 4; ++r) {
            int gi = w * 16 + lg * 4 + r;
            int dd = nd * 16 + lc;
            Out[((size_t)(b * S_ + i0 + gi) * H_ + h) * D_ + dd] = ctx[nd][r] * l_r[r];
        }
}

// ---------------------------------------------------------------------------
extern "C" void kernel_launch(void* const* d_in, const int* in_sizes, int n_in,
                              void* d_out, int out_size, void* d_ws, size_t ws_size,
                              hipStream_t stream)
{
    const float* X    = (const float*)d_in[0];
    const float* mask = (const float*)d_in[1];
    const float* Wq   = (const float*)d_in[2];
    const float* bq   = (const float*)d_in[3];
    const float* Wk   = (const float*)d_in[4];
    const float* bk   = (const float*)d_in[5];
    const float* Wv   = (const float*)d_in[6];
    const float* bv   = (const float*)d_in[7];
    const float* E    = (const float*)d_in[8];
    float* Out = (float*)d_out;

    const size_t headN = (size_t)B_ * H_ * S_ * D_;   // 4,194,304 elements
    unsigned short* Qw = (unsigned short*)d_ws;
    unsigned short* Kw = Qw + headN;
    unsigned short* Vw = Kw + headN;
    unsigned short* Ebw = Vw + headN;                  // 2047*64 bf16

    conv_e_kernel<<<dim3(128), dim3(256), 0, stream>>>(E, Ebw);
    proj_kernel<<<dim3(768), dim3(256), 0, stream>>>(X, Wq, bq, Wk, bk, Wv, bv, Qw, Kw, Vw);
    attn_kernel<<<dim3(16, 64), dim3(256), 0, stream>>>(Qw, Kw, Vw, mask, Ebw, Out);
}

// Round 2
// 216.501 us; speedup vs baseline: 1.1400x; 1.1400x over previous
//
#include <hip/hip_runtime.h>
#include <hip/hip_bf16.h>

#define B_   4
#define S_   1024
#define HID_ 1024
#define H_   16
#define D_   64

typedef __attribute__((ext_vector_type(4))) float f32x4;
typedef __attribute__((ext_vector_type(8))) __bf16 bf16v8;
typedef __attribute__((ext_vector_type(8))) unsigned short u16x8;

#define MFMA16(a, b, c) __builtin_amdgcn_mfma_f32_16x16x32_bf16((a), (b), (c), 0, 0, 0)
#define GLOAD16(gp, lp)                                                              \
    __builtin_amdgcn_global_load_lds((const __attribute__((address_space(1))) void*)(gp), \
                                     (__attribute__((address_space(3))) void*)(lp), 16, 0, 0)

__device__ __forceinline__ unsigned short f2bs_hw(float f) {
    __bf16 h = (__bf16)f;                       // hardware RNE cvt (v_cvt_pk_bf16_f32)
    return __builtin_bit_cast(unsigned short, h);
}
__device__ __forceinline__ float bs2f(unsigned short s) {
    union { unsigned u; float f; } v; v.u = ((unsigned)s) << 16;
    return v.f;
}

// ---------------------------------------------------------------------------
// Kernel 1: dist_emb f32 -> bf16
// ---------------------------------------------------------------------------
__global__ void conv_e_kernel(const float* __restrict__ E, unsigned short* __restrict__ Eb) {
    int i = (blockIdx.x * 256 + threadIdx.x) * 4;
    const int n = 2047 * 64;
    if (i + 3 < n) {
        float4 x = *(const float4*)(E + i);
        Eb[i + 0] = f2bs_hw(x.x); Eb[i + 1] = f2bs_hw(x.y);
        Eb[i + 2] = f2bs_hw(x.z); Eb[i + 3] = f2bs_hw(x.w);
    } else {
        for (int k = i; k < n; ++k) Eb[k] = f2bs_hw(E[k]);
    }
}

// ---------------------------------------------------------------------------
// Kernel 2: fused QKV projection GEMM (128x128 tiles, BK=32, 4 waves).
// ---------------------------------------------------------------------------
__global__ __launch_bounds__(256)
void proj_kernel(const float* __restrict__ X,
                 const float* __restrict__ Wq, const float* __restrict__ bq,
                 const float* __restrict__ Wk, const float* __restrict__ bk,
                 const float* __restrict__ Wv, const float* __restrict__ bv,
                 unsigned short* __restrict__ Qo, unsigned short* __restrict__ Ko,
                 unsigned short* __restrict__ Vo)
{
    __shared__ unsigned short Al[128][40];
    __shared__ unsigned short Bl[128][40];

    const int tile = blockIdx.x;
    const int rt = tile / 24, ct = tile % 24;
    const int row0 = rt * 128, col0 = ct * 128;
    const int which = col0 >> 10;
    const float* Wm   = (which == 0) ? Wq : (which == 1) ? Wk : Wv;
    const float* bias = (which == 0) ? bq : (which == 1) ? bk : bv;
    unsigned short* Out = (which == 0) ? Qo : (which == 1) ? Ko : Vo;
    const int oc0 = col0 & 1023;

    const int t = threadIdx.x;
    const int lane = t & 63, wv = t >> 6;
    const int wr = wv >> 1, wc = wv & 1;
    const int lg = lane >> 4, lc = lane & 15;

    f32x4 acc[4][4] = {};

    for (int k0 = 0; k0 < 1024; k0 += 32) {
        __syncthreads();
#pragma unroll
        for (int l = 0; l < 4; ++l) {
            int idx = l * 256 + t;
            int r = idx >> 3, kq = (idx & 7) * 4;
            float4 a = *(const float4*)(X  + (size_t)(row0 + r) * 1024 + k0 + kq);
            float4 b = *(const float4*)(Wm + (size_t)(oc0  + r) * 1024 + k0 + kq);
            short4 as, bs;
            as.x = (short)f2bs_hw(a.x); as.y = (short)f2bs_hw(a.y);
            as.z = (short)f2bs_hw(a.z); as.w = (short)f2bs_hw(a.w);
            bs.x = (short)f2bs_hw(b.x); bs.y = (short)f2bs_hw(b.y);
            bs.z = (short)f2bs_hw(b.z); bs.w = (short)f2bs_hw(b.w);
            *(short4*)&Al[r][kq] = as;
            *(short4*)&Bl[r][kq] = bs;
        }
        __syncthreads();
        bf16v8 af[4], bfg[4];
#pragma unroll
        for (int m = 0; m < 4; ++m) af[m]  = *(const bf16v8*)&Al[wr * 64 + m * 16 + lc][lg * 8];
#pragma unroll
        for (int n = 0; n < 4; ++n) bfg[n] = *(const bf16v8*)&Bl[wc * 64 + n * 16 + lc][lg * 8];
#pragma unroll
        for (int m = 0; m < 4; ++m)
#pragma unroll
            for (int n = 0; n < 4; ++n)
                acc[m][n] = MFMA16(af[m], bfg[n], acc[m][n]);
    }

#pragma unroll
    for (int m = 0; m < 4; ++m)
#pragma unroll
        for (int n = 0; n < 4; ++n) {
            int j = oc0 + wc * 64 + n * 16 + lc;
            int hh = j >> 6, dd = j & 63;
            float bv_ = bias[j];
#pragma unroll
            for (int r = 0; r < 4; ++r) {
                int i = row0 + wr * 64 + m * 16 + lg * 4 + r;
                int bb = i >> 10, ss = i & 1023;
                float v = acc[m][n][r] + bv_;
                Out[((size_t)(bb * 16 + hh) * 1024 + ss) * 64 + dd] = f2bs_hw(v);
            }
        }
}

// ---------------------------------------------------------------------------
// Kernel 3: fused attention with relative_key_query bias.
// global_load_lds + XOR-swizzled K/E staging, ring-buffered QD/E window,
// rotated-column V^T, hw bf16 converts.
// ---------------------------------------------------------------------------
__global__ __launch_bounds__(256)
void attn_kernel(const unsigned short* __restrict__ Q,
                 const unsigned short* __restrict__ K,
                 const unsigned short* __restrict__ V,
                 const float* __restrict__ mask,
                 const unsigned short* __restrict__ Eb,
                 float* __restrict__ Out)
{
    __shared__ __align__(16) unsigned short Kl[64][64];    // unit-swizzled (u ^= row&7)
    __shared__ __align__(16) unsigned short El[128][64];   // ring (slot=d&127), unit-swizzled
    __shared__ __align__(16) unsigned short VTl[64][72];   // col-rotated: jst=(j+(dd>>3)*8)&63
    __shared__ unsigned short QDl[64][132];                // ring col (slot = d&127)
    __shared__ unsigned short KDl[64][132];                // local col (c = d - dbase)
    __shared__ __align__(16) unsigned short Pl[4][16][72];
    __shared__ float maskl[64];

    const int t = threadIdx.x;
    const int lane = t & 63, w = t >> 6;
    const int lg = lane >> 4, lc = lane & 15;

    const int qt = blockIdx.x;       // 0..15
    const int bh = blockIdx.y;       // 0..63
    const int b = bh >> 4, h = bh & 15;
    const int i0 = qt * 64;

    const unsigned short* Qh = Q + (size_t)bh * S_ * D_;
    const unsigned short* Kh = K + (size_t)bh * S_ * D_;
    const unsigned short* Vh = V + (size_t)bh * S_ * D_;

    bf16v8 qf[2];
#pragma unroll
    for (int ks = 0; ks < 2; ++ks)
        qf[ks] = *(const bf16v8*)(Qh + (size_t)(i0 + w * 16 + lc) * D_ + ks * 32 + lg * 8);

    float m_r[4], l_r[4];
    f32x4 ctx[4];
#pragma unroll
    for (int r = 0; r < 4; ++r) { m_r[r] = -1e30f; l_r[r] = 0.f; }
#pragma unroll
    for (int nd = 0; nd < 4; ++nd) ctx[nd] = (f32x4){0.f, 0.f, 0.f, 0.f};

    const int row = w * 16 + lg * 4;           // this thread's 4 output rows start here

    for (int jt = 0; jt < 16; ++jt) {
        const int j0 = jt * 64;
        const int dbase = i0 - j0 + 960;       // window start in distance space
        __syncthreads();                        // (1) prev readers done

        // ---- stage K tile: global_load_lds, swizzled source units ----
#pragma unroll
        for (int l = 0; l < 2; ++l) {
            int idx = l * 256 + t;              // unit index [0,512)
            int r = idx >> 3, su = idx & 7;
            int u = su ^ (r & 7);
            GLOAD16(Kh + (size_t)(j0 + r) * 64 + u * 8,
                    &Kl[0][0] + (size_t)(l * 256 + w * 64) * 8);
        }
        // ---- stage V^T tile (reg), rotated columns ----
#pragma unroll
        for (int l = 0; l < 2; ++l) {
            int idx = l * 256 + t;
            int r = idx >> 3, cq = (idx & 7) * 8;
            u16x8 vv = *(const u16x8*)(Vh + (size_t)(j0 + r) * 64 + cq);
            int jst = (r + ((idx & 7) << 3)) & 63;
#pragma unroll
            for (int e = 0; e < 8; ++e) VTl[cq + e][jst] = vv[e];
        }
        // ---- stage E window (ring) via global_load_lds ----
        if (jt == 0) {
            const int sb0 = dbase & 127;
#pragma unroll
            for (int l = 0; l < 4; ++l) {
                int idx = l * 256 + t;          // [0,1024) units
                int sl = idx >> 3, su = idx & 7;
                int u = su ^ (sl & 7);
                int dr = dbase + ((sl - sb0) & 127);
                if (dr > 2046) dr = 2046;       // pad row, never gathered
                GLOAD16(Eb + (size_t)dr * 64 + u * 8,
                        &El[0][0] + (size_t)(l * 256 + w * 64) * 8);
            }
        } else {
            const int sb = dbase & 127;         // 0 or 64
#pragma unroll
            for (int l = 0; l < 2; ++l) {
                int idx = l * 256 + t;          // [0,512) units
                int rl = idx >> 3, su = idx & 7;
                int u = su ^ (rl & 7);          // (sb+rl)&7 == rl&7
                GLOAD16(Eb + (size_t)(dbase + rl) * 64 + u * 8,
                        &El[sb][0] + (size_t)(l * 256 + w * 64) * 8);
            }
        }
        if (t < 64) maskl[t] = mask[(size_t)b * S_ + j0 + t];
        __syncthreads();                        // (2) staging complete

        // ---- KD = K_tile @ E_win^T (8 nd), QD new half (4 nd; 8 at jt=0) ----
        bf16v8 kfa[2];
#pragma unroll
        for (int ks = 0; ks < 2; ++ks) {
            int u = (ks * 4 + lg) ^ (lc & 7);
            kfa[ks] = *(const bf16v8*)&Kl[w * 16 + lc][u * 8];
        }
#pragma unroll
        for (int nd = 0; nd < 8; ++nd) {
            f32x4 kd = (f32x4){0.f, 0.f, 0.f, 0.f};
            int sl = (dbase + nd * 16 + lc) & 127;
#pragma unroll
            for (int ks = 0; ks < 2; ++ks) {
                int u = (ks * 4 + lg) ^ (lc & 7);
                bf16v8 ef = *(const bf16v8*)&El[sl][u * 8];
                kd = MFMA16(kfa[ks], ef, kd);
            }
#pragma unroll
            for (int r = 0; r < 4; ++r)
                KDl[row + r][nd * 16 + lc] = f2bs_hw(kd[r]);
        }
#pragma unroll
        for (int nd = 0; nd < 4; ++nd) {
            f32x4 qd = (f32x4){0.f, 0.f, 0.f, 0.f};
            int slot = (dbase + nd * 16 + lc) & 127;
#pragma unroll
            for (int ks = 0; ks < 2; ++ks) {
                int u = (ks * 4 + lg) ^ (lc & 7);
                bf16v8 ef = *(const bf16v8*)&El[slot][u * 8];
                qd = MFMA16(qf[ks], ef, qd);
            }
#pragma unroll
            for (int r = 0; r < 4; ++r)
                QDl[row + r][slot] = f2bs_hw(qd[r]);
        }
        if (jt == 0) {
#pragma unroll
            for (int nd = 4; nd < 8; ++nd) {
                f32x4 qd = (f32x4){0.f, 0.f, 0.f, 0.f};
                int slot = (dbase + nd * 16 + lc) & 127;
#pragma unroll
                for (int ks = 0; ks < 2; ++ks) {
                    int u = (ks * 4 + lg) ^ (lc & 7);
                    bf16v8 ef = *(const bf16v8*)&El[slot][u * 8];
                    qd = MFMA16(qf[ks], ef, qd);
                }
#pragma unroll
                for (int r = 0; r < 4; ++r)
                    QDl[row + r][slot] = f2bs_hw(qd[r]);
            }
        }
        __syncthreads();                        // (3) QD/KD visible

        // ---- S = Q K^T ----
        f32x4 s[4];
#pragma unroll
        for (int n = 0; n < 4; ++n) {
            s[n] = (f32x4){0.f, 0.f, 0.f, 0.f};
#pragma unroll
            for (int ks = 0; ks < 2; ++ks) {
                int u = (ks * 4 + lg) ^ (lc & 7);
                bf16v8 kb = *(const bf16v8*)&Kl[n * 16 + lc][u * 8];
                s[n] = MFMA16(qf[ks], kb, s[n]);
            }
        }

        // ---- rel bias gather + mask + online softmax ----
        float mnew[4], alpha[4], rs[4];
#pragma unroll
        for (int r = 0; r < 4; ++r) {
            const int gi = row + r;
            float mx = m_r[r];
#pragma unroll
            for (int n = 0; n < 4; ++n) {
                int jj = n * 16 + lc;
                int c = gi - jj + 63;                       // [0,126]
                int slot = (dbase + c) & 127;
                float val = (s[n][r] + bs2f(QDl[gi][slot]) + bs2f(KDl[jj][c])) * 0.125f
                            + maskl[jj];
                s[n][r] = val;
                mx = fmaxf(mx, val);
            }
#pragma unroll
            for (int off = 1; off < 16; off <<= 1)
                mx = fmaxf(mx, __shfl_xor(mx, off));
            mnew[r] = mx;
            alpha[r] = __expf(m_r[r] - mx);
            m_r[r] = mx;
            rs[r] = 0.f;
        }
#pragma unroll
        for (int n = 0; n < 4; ++n)
#pragma unroll
            for (int r = 0; r < 4; ++r) {
                float p = __expf(s[n][r] - mnew[r]);
                s[n][r] = p;
                rs[r] += p;
            }
#pragma unroll
        for (int r = 0; r < 4; ++r) {
#pragma unroll
            for (int off = 1; off < 16; off <<= 1)
                rs[r] += __shfl_xor(rs[r], off);
            l_r[r] = l_r[r] * alpha[r] + rs[r];
        }
#pragma unroll
        for (int nd = 0; nd < 4; ++nd)
#pragma unroll
            for (int r = 0; r < 4; ++r)
                ctx[nd][r] *= alpha[r];

        // ---- P -> LDS (bf16), PV ----
#pragma unroll
        for (int n = 0; n < 4; ++n)
#pragma unroll
            for (int r = 0; r < 4; ++r)
                Pl[w][lg * 4 + r][n * 16 + lc] = f2bs_hw(s[n][r]);
        bf16v8 pf[2];
#pragma unroll
        for (int ks = 0; ks < 2; ++ks)
            pf[ks] = *(const bf16v8*)&Pl[w][lc][ks * 32 + lg * 8];
#pragma unroll
        for (int nd = 0; nd < 4; ++nd) {
            int vrow = nd * 16 + lc;
#pragma unroll
            for (int ks = 0; ks < 2; ++ks) {
                int jst = (ks * 32 + lg * 8 + ((vrow >> 3) << 3)) & 63;
                bf16v8 vf = *(const bf16v8*)&VTl[vrow][jst];
                ctx[nd] = MFMA16(pf[ks], vf, ctx[nd]);
            }
        }
    }

    // ---- epilogue ----
#pragma unroll
    for (int r = 0; r < 4; ++r) l_r[r] = 1.0f / l_r[r];
#pragma unroll
    for (int nd = 0; nd < 4; ++nd)
#pragma unroll
        for (int r = 0; r < 4; ++r) {
            int gi = row + r;
            int dd = nd * 16 + lc;
            Out[((size_t)(b * S_ + i0 + gi) * H_ + h) * D_ + dd] = ctx[nd][r] * l_r[r];
        }
}

// ---------------------------------------------------------------------------
extern "C" void kernel_launch(void* const* d_in, const int* in_sizes, int n_in,
                              void* d_out, int out_size, void* d_ws, size_t ws_size,
                              hipStream_t stream)
{
    const float* X    = (const float*)d_in[0];
    const float* mask = (const float*)d_in[1];
    const float* Wq   = (const float*)d_in[2];
    const float* bq   = (const float*)d_in[3];
    const float* Wk   = (const float*)d_in[4];
    const float* bk   = (const float*)d_in[5];
    const float* Wv   = (const float*)d_in[6];
    const float* bv   = (const float*)d_in[7];
    const float* E    = (const float*)d_in[8];
    float* Out = (float*)d_out;

    const size_t headN = (size_t)B_ * H_ * S_ * D_;
    unsigned short* Qw = (unsigned short*)d_ws;
    unsigned short* Kw = Qw + headN;
    unsigned short* Vw = Kw + headN;
    unsigned short* Ebw = Vw + headN;

    conv_e_kernel<<<dim3(128), dim3(256), 0, stream>>>(E, Ebw);
    proj_kernel<<<dim3(768), dim3(256), 0, stream>>>(X, Wq, bq, Wk, bk, Wv, bv, Qw, Kw, Vw);
    attn_kernel<<<dim3(16, 64), dim3(256), 0, stream>>>(Qw, Kw, Vw, mask, Ebw, Out);
}

// Round 3
// 189.582 us; speedup vs baseline: 1.3019x; 1.1420x over previous
//
#include <hip/hip_runtime.h>
#include <hip/hip_bf16.h>

#define B_   4
#define S_   1024
#define HID_ 1024
#define H_   16
#define D_   64

typedef __attribute__((ext_vector_type(4))) float f32x4;
typedef __attribute__((ext_vector_type(8))) __bf16 bf16v8;
typedef __attribute__((ext_vector_type(8))) unsigned short u16x8;

#define MFMA16(a, b, c) __builtin_amdgcn_mfma_f32_16x16x32_bf16((a), (b), (c), 0, 0, 0)
#define GLOAD16(gp, lp)                                                              \
    __builtin_amdgcn_global_load_lds((const __attribute__((address_space(1))) void*)(gp), \
                                     (__attribute__((address_space(3))) void*)(lp), 16, 0, 0)

__device__ __forceinline__ unsigned short f2bs_hw(float f) {
    __bf16 h = (__bf16)f;
    return __builtin_bit_cast(unsigned short, h);
}
__device__ __forceinline__ unsigned pack2bf(float a, float b) {
    unsigned short lo = f2bs_hw(a), hi = f2bs_hw(b);
    return (unsigned)lo | ((unsigned)hi << 16);
}
__device__ __forceinline__ float bs2f(unsigned short s) {
    union { unsigned u; float f; } v; v.u = ((unsigned)s) << 16;
    return v.f;
}

// ---------------------------------------------------------------------------
// Kernel 1: dist_emb f32 -> bf16
// ---------------------------------------------------------------------------
__global__ void conv_e_kernel(const float* __restrict__ E, unsigned short* __restrict__ Eb) {
    int i = (blockIdx.x * 256 + threadIdx.x) * 4;
    const int n = 2047 * 64;
    if (i + 3 < n) {
        float4 x = *(const float4*)(E + i);
        Eb[i + 0] = f2bs_hw(x.x); Eb[i + 1] = f2bs_hw(x.y);
        Eb[i + 2] = f2bs_hw(x.z); Eb[i + 3] = f2bs_hw(x.w);
    } else {
        for (int k = i; k < n; ++k) Eb[k] = f2bs_hw(E[k]);
    }
}

// ---------------------------------------------------------------------------
// Kernel 2: fused QKV projection GEMM (128x128 tiles, BK=32, 4 waves).
// ---------------------------------------------------------------------------
__global__ __launch_bounds__(256)
void proj_kernel(const float* __restrict__ X,
                 const float* __restrict__ Wq, const float* __restrict__ bq,
                 const float* __restrict__ Wk, const float* __restrict__ bk,
                 const float* __restrict__ Wv, const float* __restrict__ bv,
                 unsigned short* __restrict__ Qo, unsigned short* __restrict__ Ko,
                 unsigned short* __restrict__ Vo)
{
    __shared__ unsigned short Al[128][40];
    __shared__ unsigned short Bl[128][40];

    const int tile = blockIdx.x;
    const int rt = tile / 24, ct = tile % 24;
    const int row0 = rt * 128, col0 = ct * 128;
    const int which = col0 >> 10;
    const float* Wm   = (which == 0) ? Wq : (which == 1) ? Wk : Wv;
    const float* bias = (which == 0) ? bq : (which == 1) ? bk : bv;
    unsigned short* Out = (which == 0) ? Qo : (which == 1) ? Ko : Vo;
    const int oc0 = col0 & 1023;

    const int t = threadIdx.x;
    const int lane = t & 63, wv = t >> 6;
    const int wr = wv >> 1, wc = wv & 1;
    const int lg = lane >> 4, lc = lane & 15;

    f32x4 acc[4][4] = {};

    for (int k0 = 0; k0 < 1024; k0 += 32) {
        __syncthreads();
#pragma unroll
        for (int l = 0; l < 4; ++l) {
            int idx = l * 256 + t;
            int r = idx >> 3, kq = (idx & 7) * 4;
            float4 a = *(const float4*)(X  + (size_t)(row0 + r) * 1024 + k0 + kq);
            float4 b = *(const float4*)(Wm + (size_t)(oc0  + r) * 1024 + k0 + kq);
            short4 as, bs;
            as.x = (short)f2bs_hw(a.x); as.y = (short)f2bs_hw(a.y);
            as.z = (short)f2bs_hw(a.z); as.w = (short)f2bs_hw(a.w);
            bs.x = (short)f2bs_hw(b.x); bs.y = (short)f2bs_hw(b.y);
            bs.z = (short)f2bs_hw(b.z); bs.w = (short)f2bs_hw(b.w);
            *(short4*)&Al[r][kq] = as;
            *(short4*)&Bl[r][kq] = bs;
        }
        __syncthreads();
        bf16v8 af[4], bfg[4];
#pragma unroll
        for (int m = 0; m < 4; ++m) af[m]  = *(const bf16v8*)&Al[wr * 64 + m * 16 + lc][lg * 8];
#pragma unroll
        for (int n = 0; n < 4; ++n) bfg[n] = *(const bf16v8*)&Bl[wc * 64 + n * 16 + lc][lg * 8];
#pragma unroll
        for (int m = 0; m < 4; ++m)
#pragma unroll
            for (int n = 0; n < 4; ++n)
                acc[m][n] = MFMA16(af[m], bfg[n], acc[m][n]);
    }

#pragma unroll
    for (int m = 0; m < 4; ++m)
#pragma unroll
        for (int n = 0; n < 4; ++n) {
            int j = oc0 + wc * 64 + n * 16 + lc;
            int hh = j >> 6, dd = j & 63;
            float bv_ = bias[j];
#pragma unroll
            for (int r = 0; r < 4; ++r) {
                int i = row0 + wr * 64 + m * 16 + lg * 4 + r;
                int bb = i >> 10, ss = i & 1023;
                float v = acc[m][n][r] + bv_;
                Out[((size_t)(bb * 16 + hh) * 1024 + ss) * 64 + dd] = f2bs_hw(v);
            }
        }
}

// ---------------------------------------------------------------------------
// Kernel 3: fused attention with relative_key_query bias.
// Transposed+packed QD/KD stores, MFMA row-sum, paired V^T staging,
// exp2-domain online softmax.
// ---------------------------------------------------------------------------
__global__ __launch_bounds__(256)
void attn_kernel(const unsigned short* __restrict__ Q,
                 const unsigned short* __restrict__ K,
                 const unsigned short* __restrict__ V,
                 const float* __restrict__ mask,
                 const unsigned short* __restrict__ Eb,
                 float* __restrict__ Out)
{
    __shared__ __align__(16) unsigned short Kl[64][64];    // unit-swizzled (u ^= row&7)
    __shared__ __align__(16) unsigned short El[128][64];   // ring (slot=d&127), unit-swizzled
    __shared__ __align__(16) unsigned short VTl[64][72];   // col-rotated: jst=(j+(dd>>3)*8)&63
    __shared__ unsigned short QDlT[128][70];               // [slot][i]  (transposed)
    __shared__ unsigned short KDlT[128][70];               // [c][j]     (transposed)
    __shared__ __align__(16) unsigned short Pl[4][16][72];
    __shared__ float maskl[64];

    const int t = threadIdx.x;
    const int lane = t & 63, w = t >> 6;
    const int lg = lane >> 4, lc = lane & 15;

    const int qt = blockIdx.x;       // 0..15
    const int bh = blockIdx.y;       // 0..63
    const int b = bh >> 4, h = bh & 15;
    const int i0 = qt * 64;

    const float C2 = 0.125f * 1.44269504089f;   // scale into log2 domain
    const float L2E = 1.44269504089f;

    const unsigned short* Qh = Q + (size_t)bh * S_ * D_;
    const unsigned short* Kh = K + (size_t)bh * S_ * D_;
    const unsigned short* Vh = V + (size_t)bh * S_ * D_;

    bf16v8 qf[2];
#pragma unroll
    for (int ks = 0; ks < 2; ++ks)
        qf[ks] = *(const bf16v8*)(Qh + (size_t)(i0 + w * 16 + lc) * D_ + ks * 32 + lg * 8);

    // all-ones bf16 B-fragment for MFMA row-sum
    u16x8 ones_u;
#pragma unroll
    for (int e = 0; e < 8; ++e) ones_u[e] = 0x3F80;
    const bf16v8 onesf = __builtin_bit_cast(bf16v8, ones_u);

    float m_r[4];
    f32x4 lacc = (f32x4){0.f, 0.f, 0.f, 0.f};
    f32x4 ctx[4];
#pragma unroll
    for (int r = 0; r < 4; ++r) m_r[r] = -1e30f;
#pragma unroll
    for (int nd = 0; nd < 4; ++nd) ctx[nd] = (f32x4){0.f, 0.f, 0.f, 0.f};

    const int row = w * 16 + lg * 4;

    for (int jt = 0; jt < 16; ++jt) {
        const int j0 = jt * 64;
        const int dbase = i0 - j0 + 960;
        __syncthreads();                        // (1) prev readers done

        // ---- stage K tile: global_load_lds, swizzled source units ----
#pragma unroll
        for (int l = 0; l < 2; ++l) {
            int idx = l * 256 + t;
            int r = idx >> 3, su = idx & 7;
            int u = su ^ (r & 7);
            GLOAD16(Kh + (size_t)(j0 + r) * 64 + u * 8,
                    &Kl[0][0] + (size_t)(l * 256 + w * 64) * 8);
        }
        // ---- stage V^T tile: 2 rows per thread, paired dword stores ----
        {
            int a = t & 7, rb = (t >> 3) << 1;        // a: col-group, rb: even row
            int cq = a * 8;
            u16x8 v0 = *(const u16x8*)(Vh + (size_t)(j0 + rb) * 64 + cq);
            u16x8 v1 = *(const u16x8*)(Vh + (size_t)(j0 + rb + 1) * 64 + cq);
            int jst = (rb + (a << 3)) & 63;           // even
#pragma unroll
            for (int e = 0; e < 8; ++e)
                *(unsigned*)&VTl[cq + e][jst] = (unsigned)v0[e] | ((unsigned)v1[e] << 16);
        }
        // ---- stage E window (ring) via global_load_lds ----
        if (jt == 0) {
            const int sb0 = dbase & 127;
#pragma unroll
            for (int l = 0; l < 4; ++l) {
                int idx = l * 256 + t;
                int sl = idx >> 3, su = idx & 7;
                int u = su ^ (sl & 7);
                int dr = dbase + ((sl - sb0) & 127);
                if (dr > 2046) dr = 2046;
                GLOAD16(Eb + (size_t)dr * 64 + u * 8,
                        &El[0][0] + (size_t)(l * 256 + w * 64) * 8);
            }
        } else {
            const int sb = dbase & 127;
#pragma unroll
            for (int l = 0; l < 2; ++l) {
                int idx = l * 256 + t;
                int rl = idx >> 3, su = idx & 7;
                int u = su ^ (rl & 7);
                GLOAD16(Eb + (size_t)(dbase + rl) * 64 + u * 8,
                        &El[sb][0] + (size_t)(l * 256 + w * 64) * 8);
            }
        }
        if (t < 64) maskl[t] = mask[(size_t)b * S_ + j0 + t] * L2E;
        __syncthreads();                        // (2) staging complete

        // ---- KD = K_tile @ E_win^T; transposed packed stores ----
        bf16v8 kfa[2];
#pragma unroll
        for (int ks = 0; ks < 2; ++ks) {
            int u = (ks * 4 + lg) ^ (lc & 7);
            kfa[ks] = *(const bf16v8*)&Kl[w * 16 + lc][u * 8];
        }
#pragma unroll
        for (int nd = 0; nd < 8; ++nd) {
            f32x4 kd = (f32x4){0.f, 0.f, 0.f, 0.f};
            int sl = (dbase + nd * 16 + lc) & 127;
#pragma unroll
            for (int ks = 0; ks < 2; ++ks) {
                int u = (ks * 4 + lg) ^ (lc & 7);
                bf16v8 ef = *(const bf16v8*)&El[sl][u * 8];
                kd = MFMA16(kfa[ks], ef, kd);
            }
            unsigned* dst = (unsigned*)&KDlT[nd * 16 + lc][row];
            dst[0] = pack2bf(kd[0], kd[1]);
            dst[1] = pack2bf(kd[2], kd[3]);
        }
        // ---- QD: new window half (4 nd; all 8 at jt=0) ----
#pragma unroll
        for (int nd = 0; nd < 4; ++nd) {
            f32x4 qd = (f32x4){0.f, 0.f, 0.f, 0.f};
            int slot = (dbase + nd * 16 + lc) & 127;
#pragma unroll
            for (int ks = 0; ks < 2; ++ks) {
                int u = (ks * 4 + lg) ^ (lc & 7);
                bf16v8 ef = *(const bf16v8*)&El[slot][u * 8];
                qd = MFMA16(qf[ks], ef, qd);
            }
            unsigned* dst = (unsigned*)&QDlT[slot][row];
            dst[0] = pack2bf(qd[0], qd[1]);
            dst[1] = pack2bf(qd[2], qd[3]);
        }
        if (jt == 0) {
#pragma unroll
            for (int nd = 4; nd < 8; ++nd) {
                f32x4 qd = (f32x4){0.f, 0.f, 0.f, 0.f};
                int slot = (dbase + nd * 16 + lc) & 127;
#pragma unroll
                for (int ks = 0; ks < 2; ++ks) {
                    int u = (ks * 4 + lg) ^ (lc & 7);
                    bf16v8 ef = *(const bf16v8*)&El[slot][u * 8];
                    qd = MFMA16(qf[ks], ef, qd);
                }
                unsigned* dst = (unsigned*)&QDlT[slot][row];
                dst[0] = pack2bf(qd[0], qd[1]);
                dst[1] = pack2bf(qd[2], qd[3]);
            }
        }
        __syncthreads();                        // (3) QD/KD visible

        // ---- S = Q K^T ----
        f32x4 s[4];
#pragma unroll
        for (int n = 0; n < 4; ++n) {
            s[n] = (f32x4){0.f, 0.f, 0.f, 0.f};
#pragma unroll
            for (int ks = 0; ks < 2; ++ks) {
                int u = (ks * 4 + lg) ^ (lc & 7);
                bf16v8 kb = *(const bf16v8*)&Kl[n * 16 + lc][u * 8];
                s[n] = MFMA16(qf[ks], kb, s[n]);
            }
        }

        // ---- rel bias gather + mask + online softmax (log2 domain) ----
        float mnew[4], alpha[4];
#pragma unroll
        for (int r = 0; r < 4; ++r) {
            const int gi = row + r;
            float mx = m_r[r];
#pragma unroll
            for (int n = 0; n < 4; ++n) {
                int jj = n * 16 + lc;
                int c = gi - jj + 63;                       // [0,126]
                int slot = (dbase + c) & 127;
                float val = (s[n][r] + bs2f(QDlT[slot][gi]) + bs2f(KDlT[c][jj])) * C2
                            + maskl[jj];
                s[n][r] = val;
                mx = fmaxf(mx, val);
            }
#pragma unroll
            for (int off = 1; off < 16; off <<= 1)
                mx = fmaxf(mx, __shfl_xor(mx, off));
            mnew[r] = mx;
            alpha[r] = exp2f(m_r[r] - mx);
            m_r[r] = mx;
        }
#pragma unroll
        for (int n = 0; n < 4; ++n)
#pragma unroll
            for (int r = 0; r < 4; ++r)
                s[n][r] = exp2f(s[n][r] - mnew[r]);
#pragma unroll
        for (int r = 0; r < 4; ++r) lacc[r] *= alpha[r];
#pragma unroll
        for (int nd = 0; nd < 4; ++nd)
#pragma unroll
            for (int r = 0; r < 4; ++r)
                ctx[nd][r] *= alpha[r];

        // ---- P -> LDS (bf16), row-sum via MFMA, PV ----
#pragma unroll
        for (int n = 0; n < 4; ++n)
#pragma unroll
            for (int r = 0; r < 4; ++r)
                Pl[w][lg * 4 + r][n * 16 + lc] = f2bs_hw(s[n][r]);
        bf16v8 pf[2];
#pragma unroll
        for (int ks = 0; ks < 2; ++ks)
            pf[ks] = *(const bf16v8*)&Pl[w][lc][ks * 32 + lg * 8];
        lacc = MFMA16(pf[0], onesf, lacc);
        lacc = MFMA16(pf[1], onesf, lacc);
#pragma unroll
        for (int nd = 0; nd < 4; ++nd) {
            int vrow = nd * 16 + lc;
#pragma unroll
            for (int ks = 0; ks < 2; ++ks) {
                int jst = (ks * 32 + lg * 8 + ((vrow >> 3) << 3)) & 63;
                bf16v8 vf = *(const bf16v8*)&VTl[vrow][jst];
                ctx[nd] = MFMA16(pf[ks], vf, ctx[nd]);
            }
        }
    }

    // ---- epilogue ----
    float inv[4];
#pragma unroll
    for (int r = 0; r < 4; ++r) inv[r] = 1.0f / lacc[r];
#pragma unroll
    for (int nd = 0; nd < 4; ++nd)
#pragma unroll
        for (int r = 0; r < 4; ++r) {
            int gi = row + r;
            int dd = nd * 16 + lc;
            Out[((size_t)(b * S_ + i0 + gi) * H_ + h) * D_ + dd] = ctx[nd][r] * inv[r];
        }
}

// ---------------------------------------------------------------------------
extern "C" void kernel_launch(void* const* d_in, const int* in_sizes, int n_in,
                              void* d_out, int out_size, void* d_ws, size_t ws_size,
                              hipStream_t stream)
{
    const float* X    = (const float*)d_in[0];
    const float* mask = (const float*)d_in[1];
    const float* Wq   = (const float*)d_in[2];
    const float* bq   = (const float*)d_in[3];
    const float* Wk   = (const float*)d_in[4];
    const float* bk   = (const float*)d_in[5];
    const float* Wv   = (const float*)d_in[6];
    const float* bv   = (const float*)d_in[7];
    const float* E    = (const float*)d_in[8];
    float* Out = (float*)d_out;

    const size_t headN = (size_t)B_ * H_ * S_ * D_;
    unsigned short* Qw = (unsigned short*)d_ws;
    unsigned short* Kw = Qw + headN;
    unsigned short* Vw = Kw + headN;
    unsigned short* Ebw = Vw + headN;

    conv_e_kernel<<<dim3(128), dim3(256), 0, stream>>>(E, Ebw);
    proj_kernel<<<dim3(768), dim3(256), 0, stream>>>(X, Wq, bq, Wk, bk, Wv, bv, Qw, Kw, Vw);
    attn_kernel<<<dim3(16, 64), dim3(256), 0, stream>>>(Qw, Kw, Vw, mask, Ebw, Out);
}

// Round 4
// 167.159 us; speedup vs baseline: 1.4765x; 1.1341x over previous
//
#include <hip/hip_runtime.h>
#include <hip/hip_bf16.h>

#define B_   4
#define S_   1024
#define HID_ 1024
#define H_   16
#define D_   64

typedef __attribute__((ext_vector_type(4))) float f32x4;
typedef __attribute__((ext_vector_type(8))) __bf16 bf16v8;
typedef __attribute__((ext_vector_type(8))) unsigned short u16x8;

#define MFMA16(a, b, c) __builtin_amdgcn_mfma_f32_16x16x32_bf16((a), (b), (c), 0, 0, 0)
#define GLOAD16(gp, lp)                                                              \
    __builtin_amdgcn_global_load_lds((const __attribute__((address_space(1))) void*)(gp), \
                                     (__attribute__((address_space(3))) void*)(lp), 16, 0, 0)

__device__ __forceinline__ unsigned short f2bs_hw(float f) {
    __bf16 h = (__bf16)f;
    return __builtin_bit_cast(unsigned short, h);
}
__device__ __forceinline__ unsigned pack2bf(float a, float b) {
    unsigned short lo = f2bs_hw(a), hi = f2bs_hw(b);
    return (unsigned)lo | ((unsigned)hi << 16);
}
__device__ __forceinline__ float bs2f(unsigned short s) {
    union { unsigned u; float f; } v; v.u = ((unsigned)s) << 16;
    return v.f;
}

// ---------------------------------------------------------------------------
// Kernel 1: dist_emb f32 -> bf16
// ---------------------------------------------------------------------------
__global__ void conv_e_kernel(const float* __restrict__ E, unsigned short* __restrict__ Eb) {
    int i = (blockIdx.x * 256 + threadIdx.x) * 4;
    const int n = 2047 * 64;
    if (i + 3 < n) {
        float4 x = *(const float4*)(E + i);
        Eb[i + 0] = f2bs_hw(x.x); Eb[i + 1] = f2bs_hw(x.y);
        Eb[i + 2] = f2bs_hw(x.z); Eb[i + 3] = f2bs_hw(x.w);
    } else {
        for (int k = i; k < n; ++k) Eb[k] = f2bs_hw(E[k]);
    }
}

// ---------------------------------------------------------------------------
// Kernel 2: fused QKV projection GEMM (128x128 tiles, BK=32, 4 waves).
// ---------------------------------------------------------------------------
__global__ __launch_bounds__(256)
void proj_kernel(const float* __restrict__ X,
                 const float* __restrict__ Wq, const float* __restrict__ bq,
                 const float* __restrict__ Wk, const float* __restrict__ bk,
                 const float* __restrict__ Wv, const float* __restrict__ bv,
                 unsigned short* __restrict__ Qo, unsigned short* __restrict__ Ko,
                 unsigned short* __restrict__ Vo)
{
    __shared__ unsigned short Al[128][40];
    __shared__ unsigned short Bl[128][40];

    const int tile = blockIdx.x;
    const int rt = tile / 24, ct = tile % 24;
    const int row0 = rt * 128, col0 = ct * 128;
    const int which = col0 >> 10;
    const float* Wm   = (which == 0) ? Wq : (which == 1) ? Wk : Wv;
    const float* bias = (which == 0) ? bq : (which == 1) ? bk : bv;
    unsigned short* Out = (which == 0) ? Qo : (which == 1) ? Ko : Vo;
    const int oc0 = col0 & 1023;

    const int t = threadIdx.x;
    const int lane = t & 63, wv = t >> 6;
    const int wr = wv >> 1, wc = wv & 1;
    const int lg = lane >> 4, lc = lane & 15;

    f32x4 acc[4][4] = {};

    for (int k0 = 0; k0 < 1024; k0 += 32) {
        __syncthreads();
#pragma unroll
        for (int l = 0; l < 4; ++l) {
            int idx = l * 256 + t;
            int r = idx >> 3, kq = (idx & 7) * 4;
            float4 a = *(const float4*)(X  + (size_t)(row0 + r) * 1024 + k0 + kq);
            float4 b = *(const float4*)(Wm + (size_t)(oc0  + r) * 1024 + k0 + kq);
            short4 as, bs;
            as.x = (short)f2bs_hw(a.x); as.y = (short)f2bs_hw(a.y);
            as.z = (short)f2bs_hw(a.z); as.w = (short)f2bs_hw(a.w);
            bs.x = (short)f2bs_hw(b.x); bs.y = (short)f2bs_hw(b.y);
            bs.z = (short)f2bs_hw(b.z); bs.w = (short)f2bs_hw(b.w);
            *(short4*)&Al[r][kq] = as;
            *(short4*)&Bl[r][kq] = bs;
        }
        __syncthreads();
        bf16v8 af[4], bfg[4];
#pragma unroll
        for (int m = 0; m < 4; ++m) af[m]  = *(const bf16v8*)&Al[wr * 64 + m * 16 + lc][lg * 8];
#pragma unroll
        for (int n = 0; n < 4; ++n) bfg[n] = *(const bf16v8*)&Bl[wc * 64 + n * 16 + lc][lg * 8];
#pragma unroll
        for (int m = 0; m < 4; ++m)
#pragma unroll
            for (int n = 0; n < 4; ++n)
                acc[m][n] = MFMA16(af[m], bfg[n], acc[m][n]);
    }

#pragma unroll
    for (int m = 0; m < 4; ++m)
#pragma unroll
        for (int n = 0; n < 4; ++n) {
            int j = oc0 + wc * 64 + n * 16 + lc;
            int hh = j >> 6, dd = j & 63;
            float bv_ = bias[j];
#pragma unroll
            for (int r = 0; r < 4; ++r) {
                int i = row0 + wr * 64 + m * 16 + lg * 4 + r;
                int bb = i >> 10, ss = i & 1023;
                float v = acc[m][n][r] + bv_;
                Out[((size_t)(bb * 16 + hh) * 1024 + ss) * 64 + dd] = f2bs_hw(v);
            }
        }
}

// ---------------------------------------------------------------------------
// Kernel 3: fused attention, TRANSPOSED score pipeline.
// S^T = MFMA(K,Q): col i = lane, rows j in regs. Per-lane scalar softmax,
// packed b64 QD/KD stores, wave-private QD, register P exchange, float4 out.
// ---------------------------------------------------------------------------
__global__ __launch_bounds__(256)
void attn_kernel(const unsigned short* __restrict__ Q,
                 const unsigned short* __restrict__ K,
                 const unsigned short* __restrict__ V,
                 const float* __restrict__ mask,
                 const unsigned short* __restrict__ Eb,
                 float* __restrict__ Out)
{
    __shared__ __align__(16) unsigned short Kl[64][64];    // unit-swizzled (u ^= row&7)
    __shared__ __align__(16) unsigned short El[128][64];   // ring (slot=d&127), swizzled
    __shared__ __align__(16) unsigned short VTl[64][72];   // col-rotated
    __shared__ __align__(16) unsigned short QDl[4][16][136]; // wave-private [w][i=lc][slot]
    __shared__ __align__(16) unsigned short KDl[64][132];  // [j][c]
    __shared__ __align__(16) unsigned Pex[4 * 16 * 36];    // P exchange, stride 36 dw
    __shared__ float maskl[64];

    const int t = threadIdx.x;
    const int lane = t & 63, w = t >> 6;
    const int lg = lane >> 4, lc = lane & 15;

    const int bid = blockIdx.x;
    const int bh = bid & 63;         // XCD grouping: same bh -> same XCD
    const int qt = bid >> 6;
    const int b = bh >> 4, h = bh & 15;
    const int i0 = qt * 64;
    const int i_loc = w * 16 + lc;   // this lane's q-column (local)

    const float C2 = 0.125f * 1.44269504089f;
    const float L2E = 1.44269504089f;

    const unsigned short* Qh = Q + (size_t)bh * S_ * D_;
    const unsigned short* Kh = K + (size_t)bh * S_ * D_;
    const unsigned short* Vh = V + (size_t)bh * S_ * D_;

    // Q fragment (used as both A- and B-operand; identical lane mapping)
    bf16v8 qf[2];
#pragma unroll
    for (int ks = 0; ks < 2; ++ks)
        qf[ks] = *(const bf16v8*)(Qh + (size_t)(i0 + i_loc) * D_ + ks * 32 + lg * 8);

    u16x8 ones_u;
#pragma unroll
    for (int e = 0; e < 8; ++e) ones_u[e] = 0x3F80;
    const bf16v8 onesf = __builtin_bit_cast(bf16v8, ones_u);

    float m_r = -1e30f;
    f32x4 lacc = (f32x4){0.f, 0.f, 0.f, 0.f};
    f32x4 ctx[4];
#pragma unroll
    for (int nd = 0; nd < 4; ++nd) ctx[nd] = (f32x4){0.f, 0.f, 0.f, 0.f};

    unsigned* PexW = &Pex[(w * 16 + lc) * 36];

    for (int jt = 0; jt < 16; ++jt) {
        const int j0 = jt * 64;
        const int dbase = i0 - j0 + 960;
        __syncthreads();                        // (1) prev readers done

        // ---- stage K tile: global_load_lds, swizzled source units ----
#pragma unroll
        for (int l = 0; l < 2; ++l) {
            int idx = l * 256 + t;
            int r = idx >> 3, su = idx & 7;
            int u = su ^ (r & 7);
            GLOAD16(Kh + (size_t)(j0 + r) * 64 + u * 8,
                    &Kl[0][0] + (size_t)(l * 256 + w * 64) * 8);
        }
        // ---- stage V^T tile: 2 rows per thread, paired dword stores ----
        {
            int a = t & 7, rb = (t >> 3) << 1;
            int cq = a * 8;
            u16x8 v0 = *(const u16x8*)(Vh + (size_t)(j0 + rb) * 64 + cq);
            u16x8 v1 = *(const u16x8*)(Vh + (size_t)(j0 + rb + 1) * 64 + cq);
            int jst = (rb + (a << 3)) & 63;
#pragma unroll
            for (int e = 0; e < 8; ++e)
                *(unsigned*)&VTl[cq + e][jst] = (unsigned)v0[e] | ((unsigned)v1[e] << 16);
        }
        // ---- stage E window (ring) via global_load_lds ----
        if (jt == 0) {
            const int sb0 = dbase & 127;
#pragma unroll
            for (int l = 0; l < 4; ++l) {
                int idx = l * 256 + t;
                int sl = idx >> 3, su = idx & 7;
                int u = su ^ (sl & 7);
                int dr = dbase + ((sl - sb0) & 127);
                if (dr > 2046) dr = 2046;
                GLOAD16(Eb + (size_t)dr * 64 + u * 8,
                        &El[0][0] + (size_t)(l * 256 + w * 64) * 8);
            }
        } else {
            const int sb = dbase & 127;
#pragma unroll
            for (int l = 0; l < 2; ++l) {
                int idx = l * 256 + t;
                int rl = idx >> 3, su = idx & 7;
                int u = su ^ (rl & 7);
                GLOAD16(Eb + (size_t)(dbase + rl) * 64 + u * 8,
                        &El[sb][0] + (size_t)(l * 256 + w * 64) * 8);
            }
        }
        if (t < 64) maskl[t] = mask[(size_t)b * S_ + j0 + t] * L2E;
        __syncthreads();                        // (2) staging complete

        // ---- KD^T = MFMA(E, K): col j = lc, rows c in regs -> b64 stores ----
        bf16v8 kfa[2];
#pragma unroll
        for (int ks = 0; ks < 2; ++ks) {
            int u = (ks * 4 + lg) ^ (lc & 7);
            kfa[ks] = *(const bf16v8*)&Kl[w * 16 + lc][u * 8];
        }
        __builtin_amdgcn_s_setprio(1);
#pragma unroll
        for (int nd = 0; nd < 8; ++nd) {
            f32x4 kd = (f32x4){0.f, 0.f, 0.f, 0.f};
            int sl = (dbase + nd * 16 + lc) & 127;
#pragma unroll
            for (int ks = 0; ks < 2; ++ks) {
                int u = (ks * 4 + lg) ^ (lc & 7);
                bf16v8 ef = *(const bf16v8*)&El[sl][u * 8];
                kd = MFMA16(ef, kfa[ks], kd);   // A=E rows c, B=K cols j
            }
            uint2 pk;
            pk.x = pack2bf(kd[0], kd[1]);
            pk.y = pack2bf(kd[2], kd[3]);
            *(uint2*)&KDl[w * 16 + lc][nd * 16 + lg * 4] = pk;
        }
        // ---- QD^T = MFMA(E, Q): wave-private, ring cols ----
#pragma unroll
        for (int nd = 0; nd < 4; ++nd) {
            f32x4 qd = (f32x4){0.f, 0.f, 0.f, 0.f};
            int sl = (dbase + nd * 16 + lc) & 127;
#pragma unroll
            for (int ks = 0; ks < 2; ++ks) {
                int u = (ks * 4 + lg) ^ (lc & 7);
                bf16v8 ef = *(const bf16v8*)&El[sl][u * 8];
                qd = MFMA16(ef, qf[ks], qd);
            }
            int slot0 = ((dbase & 127) + nd * 16 + lg * 4) & 127;
            uint2 pk;
            pk.x = pack2bf(qd[0], qd[1]);
            pk.y = pack2bf(qd[2], qd[3]);
            *(uint2*)&QDl[w][lc][slot0] = pk;
        }
        if (jt == 0) {
#pragma unroll
            for (int nd = 4; nd < 8; ++nd) {
                f32x4 qd = (f32x4){0.f, 0.f, 0.f, 0.f};
                int sl = (dbase + nd * 16 + lc) & 127;
#pragma unroll
                for (int ks = 0; ks < 2; ++ks) {
                    int u = (ks * 4 + lg) ^ (lc & 7);
                    bf16v8 ef = *(const bf16v8*)&El[sl][u * 8];
                    qd = MFMA16(ef, qf[ks], qd);
                }
                int slot0 = ((dbase & 127) + nd * 16 + lg * 4) & 127;
                uint2 pk;
                pk.x = pack2bf(qd[0], qd[1]);
                pk.y = pack2bf(qd[2], qd[3]);
                *(uint2*)&QDl[w][lc][slot0] = pk;
            }
        }
        __builtin_amdgcn_s_setprio(0);
        __syncthreads();                        // (3) KDl visible

        // ---- S^T = MFMA(K, Q): col i = lc, rows j = n*16+4lg+r ----
        f32x4 s[4];
#pragma unroll
        for (int n = 0; n < 4; ++n) {
            s[n] = (f32x4){0.f, 0.f, 0.f, 0.f};
#pragma unroll
            for (int ks = 0; ks < 2; ++ks) {
                int u = (ks * 4 + lg) ^ (lc & 7);
                bf16v8 kb = *(const bf16v8*)&Kl[n * 16 + lc][u * 8];
                s[n] = MFMA16(kb, qf[ks], s[n]);
            }
        }

        // ---- rel gathers + mask + per-lane online softmax ----
        const unsigned short* QDw = &QDl[w][lc][0];
        float vmax = -1e30f;
#pragma unroll
        for (int n = 0; n < 4; ++n) {
            int jb = n * 16 + lg * 4;
            float4 mk = *(const float4*)&maskl[jb];
            int kbase = jb * 131 + i_loc + 63;          // KDl flat: j*132 + c
            int qbase = dbase + i_loc - jb + 63;
#pragma unroll
            for (int r = 0; r < 4; ++r) {
                float qdv = bs2f(QDw[(qbase - r) & 127]);
                float kdv = bs2f((&KDl[0][0])[kbase + 131 * r]);
                float mkr = (r == 0) ? mk.x : (r == 1) ? mk.y : (r == 2) ? mk.z : mk.w;
                float val = (s[n][r] + qdv + kdv) * C2 + mkr;
                s[n][r] = val;
                vmax = fmaxf(vmax, val);
            }
        }
        vmax = fmaxf(vmax, __shfl_xor(vmax, 16));
        vmax = fmaxf(vmax, __shfl_xor(vmax, 32));
        float mnew = fmaxf(m_r, vmax);
        float alpha = exp2f(m_r - mnew);
        m_r = mnew;

#pragma unroll
        for (int n = 0; n < 4; ++n)
#pragma unroll
            for (int r = 0; r < 4; ++r)
                s[n][r] = exp2f(s[n][r] - mnew);

#pragma unroll
        for (int r = 0; r < 4; ++r) lacc[r] *= alpha;
#pragma unroll
        for (int nd = 0; nd < 4; ++nd)
#pragma unroll
            for (int r = 0; r < 4; ++r)
                ctx[nd][r] *= alpha;

        // ---- P exchange (wave-synchronous LDS, no barrier) ----
#pragma unroll
        for (int n = 0; n < 4; ++n) {
            uint2 pk;
            pk.x = pack2bf(s[n][0], s[n][1]);
            pk.y = pack2bf(s[n][2], s[n][3]);
            *(uint2*)&PexW[n * 8 + lg * 2] = pk;
        }
        bf16v8 pfB[2];
#pragma unroll
        for (int ks = 0; ks < 2; ++ks) {
            int nc = 2 * ks + (lg >> 1);
            pfB[ks] = *(const bf16v8*)&PexW[nc * 8 + (lg & 1) * 4];
        }

        // ---- l-sum + PV ----
        __builtin_amdgcn_s_setprio(1);
        lacc = MFMA16(onesf, pfB[0], lacc);
        lacc = MFMA16(onesf, pfB[1], lacc);
#pragma unroll
        for (int nd = 0; nd < 4; ++nd) {
            int vrow = nd * 16 + lc;
#pragma unroll
            for (int ks = 0; ks < 2; ++ks) {
                int jst = (ks * 32 + lg * 8 + ((vrow >> 3) << 3)) & 63;
                bf16v8 vf = *(const bf16v8*)&VTl[vrow][jst];
                ctx[nd] = MFMA16(vf, pfB[ks], ctx[nd]);   // A=V^T rows d, B=P^T cols i
            }
        }
        __builtin_amdgcn_s_setprio(0);
    }

    // ---- epilogue: ctx^T[d][i], d contiguous in regs -> float4 stores ----
    float inv = 1.0f / lacc[0];
    float* outp = Out + ((size_t)(b * S_ + i0 + i_loc) * H_ + h) * D_;
#pragma unroll
    for (int nd = 0; nd < 4; ++nd) {
        float4 o;
        o.x = ctx[nd][0] * inv;
        o.y = ctx[nd][1] * inv;
        o.z = ctx[nd][2] * inv;
        o.w = ctx[nd][3] * inv;
        *(float4*)(outp + nd * 16 + lg * 4) = o;
    }
}

// ---------------------------------------------------------------------------
extern "C" void kernel_launch(void* const* d_in, const int* in_sizes, int n_in,
                              void* d_out, int out_size, void* d_ws, size_t ws_size,
                              hipStream_t stream)
{
    const float* X    = (const float*)d_in[0];
    const float* mask = (const float*)d_in[1];
    const float* Wq   = (const float*)d_in[2];
    const float* bq   = (const float*)d_in[3];
    const float* Wk   = (const float*)d_in[4];
    const float* bk   = (const float*)d_in[5];
    const float* Wv   = (const float*)d_in[6];
    const float* bv   = (const float*)d_in[7];
    const float* E    = (const float*)d_in[8];
    float* Out = (float*)d_out;

    const size_t headN = (size_t)B_ * H_ * S_ * D_;
    unsigned short* Qw = (unsigned short*)d_ws;
    unsigned short* Kw = Qw + headN;
    unsigned short* Vw = Kw + headN;
    unsigned short* Ebw = Vw + headN;

    conv_e_kernel<<<dim3(128), dim3(256), 0, stream>>>(E, Ebw);
    proj_kernel<<<dim3(768), dim3(256), 0, stream>>>(X, Wq, bq, Wk, bk, Wv, bv, Qw, Kw, Vw);
    attn_kernel<<<dim3(1024), dim3(256), 0, stream>>>(Qw, Kw, Vw, mask, Ebw, Out);
}